// Round 13
// baseline (246.155 us; speedup 1.0000x reference)
//
#include <hip/hip_runtime.h>

typedef unsigned short u16;
typedef unsigned int   u32;
typedef __bf16  bf16x8 __attribute__((ext_vector_type(8)));
typedef float   f32x4  __attribute__((ext_vector_type(4)));
typedef float   f32x16 __attribute__((ext_vector_type(16)));
typedef u16     u16x4  __attribute__((ext_vector_type(4)));
typedef u16     u16x8  __attribute__((ext_vector_type(8)));
typedef u32     u32x4  __attribute__((ext_vector_type(4)));

#define S_LEN 2048
#define NH 32
#define NKVH 8
#define HD 128
#define QKVST 6144          /* packed QKV row stride  */
#define AOST  4096          /* attn-out row stride    */
#define ATT_SCALE 0.08838834764831845f
#define LOG2E 1.4426950408889634f
#define QSC2 (ATT_SCALE * LOG2E)
#define RESCALE_THR2 11.5f

__device__ __forceinline__ u16 f2bf(float f){
  u32 u = __builtin_bit_cast(u32, f);
  u += 0x7FFFu + ((u >> 16) & 1u);
  return (u16)(u >> 16);
}
__device__ __forceinline__ u32 cvtpk(float lo, float hi){
  u32 d;
  asm("v_cvt_pk_bf16_f32 %0, %1, %2" : "=v"(d) : "v"(lo), "v"(hi));
  return d;
}
// async global->LDS, 16B per lane. Dest must be wave-uniform base + lane*16.
__device__ __forceinline__ void gload_lds16(const u16* g, u16* l){
  __builtin_amdgcn_global_load_lds(
      (const __attribute__((address_space(1))) void*)g,
      (__attribute__((address_space(3))) void*)l, 16, 0, 0);
}

// ------------- fused f32 -> bf16 convert of ALL inputs (one launch) --------
__global__ void cvt_all_kernel(const f32x4* __restrict__ hs, const f32x4* __restrict__ wq,
                               const f32x4* __restrict__ wk, const f32x4* __restrict__ wv,
                               const f32x4* __restrict__ wo, u16x4* __restrict__ out){
  int i = blockIdx.x * 256 + threadIdx.x;          // 0 .. 6291455
  const f32x4* src; int off;
  if      (i < 1048576){ src = hs; off = i; }
  else if (i < 3145728){ src = wq; off = i - 1048576; }
  else if (i < 3670016){ src = wk; off = i - 3145728; }
  else if (i < 4194304){ src = wv; off = i - 3670016; }
  else                 { src = wo; off = i - 4194304; }
  f32x4 v = src[off];
  u16x4 o;
  o[0] = f2bf(v[0]); o[1] = f2bf(v[1]); o[2] = f2bf(v[2]); o[3] = f2bf(v[3]);
  out[i] = o;
}

// ---------------- GEMM: C[M][N] = X[M][K] @ W[N][K]^T (bf16 in, f32 acc) ----
// (unchanged from R12)
template<int OUT_BF16, int ROPE, int BM, int BN>
__global__ __launch_bounds__(256, 2)
void gemm_bt_kernel(const u16* __restrict__ X, const u16* __restrict__ W,
                    void* __restrict__ Cv, int M, int N, int K,
                    const float* __restrict__ cosv, const float* __restrict__ sinv){
  __shared__ __align__(16) u16 As[2][2][BM * 32];
  __shared__ __align__(16) u16 Bs[2][2][BN * 32];
  const int MI = BM / 32, NJ = BN / 32;
  const int m0 = blockIdx.y * BM, n0 = blockIdx.x * BN;
  const int tid = threadIdx.x;
  const int wave = tid >> 6, lane = tid & 63;
  const int wm = wave >> 1, wn = wave & 1;
  const int g = lane >> 4, ln = lane & 15;
  const int r0 = tid >> 2;
  const int cc = (tid & 3) * 8;
  f32x4 acc[MI][NJ] = {};
  const u16* xa0 = X + (size_t)(m0 + r0) * K + cc;
  const u16* xa1 = X + (size_t)(m0 + r0 + 64) * K + cc;
  const u16* wb0 = W + (size_t)(n0 + r0) * K + cc;
  const u16* wb1 = W + (size_t)(n0 + r0 + 64) * K + cc;

  auto stage = [&](int buf, int k0){
    #pragma unroll
    for (int s = 0; s < 2; s++){
      const int kc = k0 + s * 32;
      gload_lds16(xa0 + kc, &As[buf][s][tid * 8]);
      if (BM == 128) gload_lds16(xa1 + kc, &As[buf][s][2048 + tid * 8]);
      gload_lds16(wb0 + kc, &Bs[buf][s][tid * 8]);
      if (BN == 128) gload_lds16(wb1 + kc, &Bs[buf][s][2048 + tid * 8]);
    }
  };

  stage(0, 0);
  __syncthreads();
  int cur = 0;
  for (int k0 = 0; k0 < K; k0 += 64){
    if (k0 + 64 < K) stage(cur ^ 1, k0 + 64);
    #pragma unroll
    for (int s = 0; s < 2; s++){
      bf16x8 a[MI], b[NJ];
      #pragma unroll
      for (int f = 0; f < MI; f++) a[f] = *(const bf16x8*)&As[cur][s][(wm * (BM / 2) + f * 16 + ln) * 32 + g * 8];
      #pragma unroll
      for (int f = 0; f < NJ; f++) b[f] = *(const bf16x8*)&Bs[cur][s][(wn * (BN / 2) + f * 16 + ln) * 32 + g * 8];
      __builtin_amdgcn_s_setprio(1);
      #pragma unroll
      for (int i = 0; i < MI; i++)
        #pragma unroll
        for (int j = 0; j < NJ; j++)
          acc[i][j] = __builtin_amdgcn_mfma_f32_16x16x32_bf16(a[i], b[j], acc[i][j], 0, 0, 0);
      __builtin_amdgcn_s_setprio(0);
    }
    __syncthreads();
    cur ^= 1;
  }
  if (ROPE && BN == 128){
    if (wn == 0 && n0 < 5120){
      #pragma unroll
      for (int i = 0; i < MI; i++)
        #pragma unroll
        for (int r = 0; r < 4; r++){
          const int row = m0 + wm * (BM / 2) + i * 16 + g * 4 + r;
          #pragma unroll
          for (int j = 0; j < 2; j++){
            const int d = j * 16 + ln;
            float c  = cosv[row * 64 + d];
            float sn = sinv[row * 64 + d];
            float x0 = acc[i][j][r], x1 = acc[i][j + 2][r];
            acc[i][j][r]     = x0 * c - x1 * sn;
            acc[i][j + 2][r] = x1 * c + x0 * sn;
          }
        }
    }
    if (n0 < 4096){
      #pragma unroll
      for (int i = 0; i < MI; i++)
        #pragma unroll
        for (int j = 0; j < NJ; j++)
          #pragma unroll
          for (int r = 0; r < 4; r++) acc[i][j][r] *= QSC2;
    }
  }
  #pragma unroll
  for (int i = 0; i < MI; i++)
    #pragma unroll
    for (int j = 0; j < NJ; j++)
      #pragma unroll
      for (int r = 0; r < 4; r++){
        int row = m0 + wm * (BM / 2) + i * 16 + g * 4 + r;
        int col = n0 + wn * (BN / 2) + j * 16 + ln;
        if (OUT_BF16) ((u16*)Cv)[(size_t)row * N + col] = f2bf(acc[i][j][r]);
        else          ((float*)Cv)[(size_t)row * N + col] = acc[i][j][r];
      }
}

// ---------------- V transpose: VT[kvh][vd][s] from packed QKV -------------
__global__ void vtrans_kernel(const u16* __restrict__ QKV, u16* __restrict__ VT){
  int idx = blockIdx.x * 256 + threadIdx.x;
  if (idx >= NKVH * HD * S_LEN) return;
  int s   = idx & (S_LEN - 1);
  int vd  = (idx >> 11) & (HD - 1);
  int kvh = idx >> 18;
  VT[idx] = QKV[(size_t)s * QKVST + 5120 + kvh * HD + vd];
}

// ---------------- causal flash attention, swapped-operand 32x32 MFMA -------
// GQA-shared staging: block = (kvh, 64-row q-stripe); 8 waves = 4 heads x
// 2 q-halves, ALL sharing one K/V double-buffer -> staged bytes and barriers
// per wave-tile HALVED vs R12 (which staged the same K/V tile once per head).
// 256 blocks (8 kvh x 32 stripes), LPT qt-desc, 64KB LDS (single array so the
// epilogue reuses all of it as the O-transpose arena), 8 waves/CU while live.
// Inner math identical to the verified R11 kernel: QK = mfma(K,Q) -> in-lane
// softmax (q = l31), cvt_pk + permlane32_swap P-pack, PV = mfma(V,P),
// defer-max, sink-in-init, exp2 domain.
__global__ __launch_bounds__(512, 2)
void attn_kernel(const u16* __restrict__ QKV, const u16* __restrict__ VT,
                 const float* __restrict__ sinkb, u16* __restrict__ AO){
  __shared__ __align__(16) u16 lds[4][32 * 256];  // [K0,K1,V0,V1] 16KB each
  const int b    = blockIdx.x;
  const int kvh  = b & 7;                  // XCD-aligned kv-head
  const int qt   = 31 - (b >> 3);          // LPT: longest stripes first
  const int tid  = threadIdx.x;
  const int w    = tid >> 6;               // 0..7: head (w>>1), q-half (w&1)
  const int head = kvh * 4 + (w >> 1);
  const int lane = tid & 63;
  const int l31  = lane & 31, hi = lane >> 5;
  const int q0   = qt * 64;
  const int qw   = q0 + (w & 1) * 32;      // wave's 32 q-rows

  const u16* Kbase = QKV + 4096 + kvh * HD;           // + row*QKVST
  const u16* Vbase = VT + (size_t)kvh * HD * S_LEN;   // + vd*S_LEN + key

  // stage tile kt (64 keys): 1024 K-chunks + 1024 V-chunks over 512 threads
  auto stage = [&](int buf, int kt){
    const int k0 = kt * 64;
    #pragma unroll
    for (int p = 0; p < 2; p++){
      int idx = p * 512 + tid;             // K: row r(32) x chunk c(32)
      int r = idx >> 5, c = idx & 31;
      int cs = c ^ r;
      int key = r * 2 + (cs >> 4), d8 = (cs & 15) * 8;
      gload_lds16(Kbase + (size_t)(k0 + key) * QKVST + d8, &lds[buf][idx * 8]);
    }
    #pragma unroll
    for (int p = 0; p < 2; p++){
      int idx = p * 512 + tid;             // V: row r(32) x chunk c(32)
      int r = idx >> 5, c = idx & 31;
      int cs = c ^ r;
      int vd = r * 4 + (cs >> 3), k8 = (cs & 7) * 8;
      gload_lds16(Vbase + (size_t)vd * S_LEN + k0 + k8, &lds[2 + buf][idx * 8]);
    }
  };

  // Q as B-frags (pre-scaled by ATT_SCALE*log2e): lane holds col q = l31
  bf16x8 qB[8];
  const u16* qrow = QKV + (size_t)(qw + l31) * QKVST + head * HD;
  #pragma unroll
  for (int t = 0; t < 8; t++) qB[t] = *(const bf16x8*)(qrow + t * 16 + hi * 8);

  // sink folded into init: m = sink*log2e; L starts at 1 (counted once, hi=0)
  float m  = sinkb[head] * LOG2E;
  float Ll = (hi == 0) ? 1.f : 0.f;
  f32x16 O[4] = {};

  const int nkt = qt + 1;
  stage(0, 0);
  __syncthreads();
  int cur = 0;

  for (int kt = 0; kt < nkt; kt++){
    const int k0 = kt * 64;
    if (kt + 1 < nkt) stage(cur ^ 1, kt + 1);

    if (k0 < qw + 32){                     // wave-uniform skip of masked tiles
      const u16* Kc = lds[cur];
      const u16* Vc = lds[2 + cur];
      f32x16 sc0 = {}, sc1 = {};
      const int krow0 = (l31 >> 1);
      const int kc0   = ((l31 & 1) << 4) | hi;
      __builtin_amdgcn_s_setprio(1);
      #pragma unroll
      for (int t = 0; t < 8; t++){
        bf16x8 ka0 = *(const bf16x8*)&Kc[krow0 * 256 + ((kc0 + 2 * t) ^ krow0) * 8];
        bf16x8 ka1 = *(const bf16x8*)&Kc[(16 + krow0) * 256 + ((kc0 + 2 * t) ^ (16 + krow0)) * 8];
        sc0 = __builtin_amdgcn_mfma_f32_32x32x16_bf16(ka0, qB[t], sc0, 0, 0, 0);
        sc1 = __builtin_amdgcn_mfma_f32_32x32x16_bf16(ka1, qB[t], sc1, 0, 0, 0);
      }
      __builtin_amdgcn_s_setprio(0);

      if (k0 + 63 > qw){
        const int qg = qw + l31;
        #pragma unroll
        for (int r = 0; r < 16; r++){
          int keyr = k0 + (r & 3) + 8 * (r >> 2) + 4 * hi;
          if (keyr      > qg) sc0[r] = -1e30f;
          if (keyr + 32 > qg) sc1[r] = -1e30f;
        }
      }
      // tile max: v_max3-friendly tree over 32 values + partner swap
      float m4[4];
      #pragma unroll
      for (int j = 0; j < 4; j++){
        float a = fmaxf(fmaxf(sc0[j*4], sc0[j*4+1]), fmaxf(sc0[j*4+2], sc0[j*4+3]));
        float c = fmaxf(fmaxf(sc1[j*4], sc1[j*4+1]), fmaxf(sc1[j*4+2], sc1[j*4+3]));
        m4[j] = fmaxf(a, c);
      }
      float mx = fmaxf(fmaxf(m4[0], m4[1]), fmaxf(m4[2], m4[3]));
      mx = fmaxf(mx, __shfl_xor(mx, 32));
      if (!__all(mx <= m + RESCALE_THR2)){
        float mn = fmaxf(m, mx);
        float sf = exp2f(m - mn);
        m = mn;
        #pragma unroll
        for (int n = 0; n < 4; n++)
          #pragma unroll
          for (int r = 0; r < 16; r++) O[n][r] *= sf;
        Ll *= sf;
      }
      float p0[16], p1[16];
      #pragma unroll
      for (int r = 0; r < 16; r++){ p0[r] = exp2f(sc0[r] - m); Ll += p0[r]; }
      #pragma unroll
      for (int r = 0; r < 16; r++){ p1[r] = exp2f(sc1[r] - m); Ll += p1[r]; }

      __builtin_amdgcn_s_setprio(1);
      #pragma unroll
      for (int c = 0; c < 4; c++){
        const float* ps = (c & 2) ? p1 : p0;
        const int bb = (c & 1) * 8;
        u32 wa = cvtpk(ps[bb + 0], ps[bb + 1]);
        u32 wb = cvtpk(ps[bb + 2], ps[bb + 3]);
        u32 wc = cvtpk(ps[bb + 4], ps[bb + 5]);
        u32 wd = cvtpk(ps[bb + 6], ps[bb + 7]);
        asm("v_permlane32_swap_b32 %0, %1" : "+v"(wa), "+v"(wc));
        asm("v_permlane32_swap_b32 %0, %1" : "+v"(wb), "+v"(wd));
        u32x4 wv_; wv_[0] = wa; wv_[1] = wb; wv_[2] = wc; wv_[3] = wd;
        bf16x8 pf = __builtin_bit_cast(bf16x8, wv_);
        #pragma unroll
        for (int n = 0; n < 4; n++){
          const int vrow = n * 8 + (l31 >> 2);
          const int vcc  = ((l31 & 3) << 3) | (c << 1) | hi;
          bf16x8 va = *(const bf16x8*)&Vc[vrow * 256 + (vcc ^ vrow) * 8];
          O[n] = __builtin_amdgcn_mfma_f32_32x32x16_bf16(va, pf, O[n], 0, 0, 0);
        }
      }
      __builtin_amdgcn_s_setprio(0);
    }
    __syncthreads();                       // drains prefetch vmcnt + reuse guard
    cur ^= 1;
  }

  // epilogue: in-lane 1/l; transpose O via the whole 64KB LDS as arena
  // (arena row rr = w*32 + l31 -> head = kvh*4 + (rr>>6), q = q0 + (rr&63))
  float l = Ll + __shfl_xor(Ll, 32);
  float inv = 1.f / l;
  u16* arena = &lds[0][0];                 // 256 rows x 256B = 64KB
  const int rr = w * 32 + l31;
  #pragma unroll
  for (int n = 0; n < 4; n++)
    #pragma unroll
    for (int r = 0; r < 16; r++){
      int vd = n * 32 + (r & 3) + 8 * (r >> 2) + 4 * hi;
      int ch = (vd >> 3) ^ (l31 & 15);
      arena[rr * 128 + ch * 8 + (vd & 7)] = f2bf(O[n][r] * inv);
    }
  __syncthreads();
  #pragma unroll
  for (int p = 0; p < 8; p++){
    int idx = p * 512 + tid;               // 4096 chunks: row(256) x c(16)
    int row = idx >> 4, c = idx & 15;
    u16x8 v = *(const u16x8*)&arena[row * 128 + ((c ^ (row & 15)) * 8)];
    *(u16x8*)&AO[(size_t)(q0 + (row & 63)) * AOST + (kvh * 4 + (row >> 6)) * HD + c * 8] = v;
  }
}

// ---------------- host-side launch ----------------
extern "C" void kernel_launch(void* const* d_in, const int* in_sizes, int n_in,
                              void* d_out, int out_size, void* d_ws, size_t ws_size,
                              hipStream_t stream){
  (void)in_sizes; (void)n_in; (void)out_size; (void)ws_size;
  const float* hs    = (const float*)d_in[0];
  const float* cosv  = (const float*)d_in[1];
  const float* sinv  = (const float*)d_in[2];
  /* d_in[3] attention_mask: pure causal triu(NEG,1) - implemented directly */
  const float* Wq    = (const float*)d_in[4];
  const float* Wk    = (const float*)d_in[5];
  const float* Wv    = (const float*)d_in[6];
  const float* Wo    = (const float*)d_in[7];
  const float* sinkb = (const float*)d_in[8];
  float* out = (float*)d_out;

  char* ws = (char*)d_ws;
  u16* XB    = (u16*)(ws);                  //  8,388,608  X bf16 [2048][2048]
  u16* WQKVB = (u16*)(ws + 8388608);        // 25,165,824  Wqkv bf16 [6144][2048]
  u16* WOB   = (u16*)(ws + 33554432);       // 16,777,216  Wo bf16 [2048][4096]
  u16* QKV   = (u16*)(ws + 50331648);       // 25,165,824  QKV bf16 [2048][6144]
  u16* VT    = (u16*)(ws + 75497472);       //  4,194,304  V^T bf16 [8][128][2048]
  u16* AO    = (u16*)(ws + 79691776);       // 16,777,216  attn out bf16 [2048][4096]

  cvt_all_kernel<<<24576, 256, 0, stream>>>((const f32x4*)hs, (const f32x4*)Wq,
                                            (const f32x4*)Wk, (const f32x4*)Wv,
                                            (const f32x4*)Wo, (u16x4*)ws);

  // fused QKV projection + RoPE + Q-scale(log2e)
  gemm_bt_kernel<1, 1, 64, 128><<<dim3(48, 32), 256, 0, stream>>>(XB, WQKVB, QKV, 2048, 6144, 2048, cosv, sinv);

  vtrans_kernel<<<8192, 256, 0, stream>>>(QKV, VT);

  // attention: 256 blocks (kvh x 64-row stripe), 8 waves = 4 heads x 2 halves
  attn_kernel<<<dim3(256), 512, 0, stream>>>(QKV, VT, sinkb, AO);

  // output projection (f32 out)
  gemm_bt_kernel<0, 0, 128, 64><<<dim3(32, 16), 256, 0, stream>>>(AO, WOB, out, 2048, 2048, 4096, nullptr, nullptr);
}